// Round 1
// baseline (109.015 us; speedup 1.0000x reference)
//
#include <hip/hip_runtime.h>

// Acrobot GN step, fused bf16-MFMA implementation.
// rows = 2*B (batch x {edge/node} index). Four layers:
//   G1': e1  = relu(A1 @ in32)         A1 = [We1[10:17] ; be1]^T  (K=32, bias folded via const-1 feature)
//   G2': e2  = relu(A2 @ e1 + be2)     A2 = We2^T                 (K=128)
//   G3': hdd = relu(A3 @ e2[row^1] + nodes@Wn1[10:12] + bn1)      A3 = Wn1[12:140]^T (K=128)
//   G4 : delta = hdd^T @ Wn2 + bn2  (VALU from MFMA accumulators + shfl butterfly)
// out = x + scatter(delta)

typedef __attribute__((ext_vector_type(8))) short bf16x8;
typedef __attribute__((ext_vector_type(4))) float f32x4;

__device__ __forceinline__ unsigned short f2bf(float f) {
  union { float f; unsigned u; } v; v.f = f;
  return (unsigned short)((v.u + 0x7FFFu + ((v.u >> 16) & 1u)) >> 16);  // RNE
}

// ---------------- weight prep: build bf16 transposed A-operand images in ws ----------------
// ws layout (shorts): A1 [128j][32k] @0 ; A2=We2^T [128j][128k] @4096 ; A3=Wn1[12:]^T @20480
__global__ void gn_prep(const float* __restrict__ We1, const float* __restrict__ be1,
                        const float* __restrict__ We2, const float* __restrict__ Wn1,
                        unsigned short* __restrict__ wsA) {
  int t = blockIdx.x * 256 + threadIdx.x;
  if (t < 4096) {
    int j = t >> 5, k = t & 31;
    float v = (k < 7) ? We1[(10 + k) * 128 + j] : ((k == 7) ? be1[j] : 0.0f);
    wsA[t] = f2bf(v);
  } else if (t < 20480) {
    int t2 = t - 4096; int j = t2 >> 7, k = t2 & 127;
    wsA[t] = f2bf(We2[k * 128 + j]);
  } else if (t < 36864) {
    int t2 = t - 20480; int j = t2 >> 7, k = t2 & 127;
    wsA[t] = f2bf(Wn1[(12 + k) * 128 + j]);
  }
}

// ---------------- main fused kernel ----------------
#define NTILES 2048   // 262144 rows / 128 rows per tile

__global__ __launch_bounds__(512, 2) void gn_main(
    const float* __restrict__ x, const float* __restrict__ u,
    const float* __restrict__ nmean, const float* __restrict__ nstd,
    const float* __restrict__ emean, const float* __restrict__ estd,
    const float* __restrict__ be2, const float* __restrict__ bn1,
    const float* __restrict__ Wn1, const float* __restrict__ Wn2,
    const float* __restrict__ bn2,
    const unsigned short* __restrict__ wsA,
    float* __restrict__ out)
{
  // 64KB LDS total. buf1 prefix (8KB) doubles as in32 staging; e1buf prefix (2KB) doubles as pdelta.
  __shared__ __align__(16) unsigned short e1buf[128 * 128];  // e1 [row][128k] bf16, swizzled
  __shared__ __align__(16) unsigned short buf1[128 * 128];   // in32 [row][32k] then e2 [row][128k]

  const int tid  = threadIdx.x;
  const int lane = tid & 63;
  const int wave = tid >> 6;
  const int Mg   = wave & 1;    // M half (feature dim half)
  const int Ng   = wave >> 1;   // N group (row groups of 32)
  const int c15  = lane & 15;
  const int g    = lane >> 4;   // 0..3

  // ---- A-operand fragments, loaded once, held in VGPRs (16+64+64 = 144 regs) ----
  bf16x8 A1[4], A2f[4][4], A3f[4][4];
  const int jbw = Mg * 64;
  #pragma unroll
  for (int m = 0; m < 4; ++m) {
    int j = jbw + m * 16 + c15;
    A1[m] = *(const bf16x8*)(wsA + j * 32 + g * 8);
    #pragma unroll
    for (int kk = 0; kk < 4; ++kk) {
      A2f[m][kk] = *(const bf16x8*)(wsA + 4096  + j * 128 + kk * 32 + g * 8);
      A3f[m][kk] = *(const bf16x8*)(wsA + 20480 + j * 128 + kk * 32 + g * 8);
    }
  }

  const float nm0 = nmean[0], nm1 = nmean[1];
  const float is0 = 1.0f / nstd[0], is1 = 1.0f / nstd[1];
  const float em0 = emean[0], ie0 = 1.0f / estd[0];
  const float cea1 = (0.0f - emean[1]) / estd[1];
  const float cea2 = (0.0f - emean[2]) / estd[2];
  const float bn20 = bn2[0], bn21 = bn2[1];

  for (int tile = blockIdx.x; tile < NTILES; tile += gridDim.x) {
    const int rowbase = tile * 128;

    // ---------- stage0: build in32 (bf16, 32 feats/row; feats 8..31 zero) into buf1 prefix ----------
    {
      int row = tid & 127;
      int cc  = tid >> 7;                       // 16B chunk 0..3 (wave-uniform)
      int off = row * 64 + ((cc * 16) ^ ((row & 3) << 4));
      bf16x8 val;
      #pragma unroll
      for (int i = 0; i < 8; ++i) val[i] = 0;
      if (cc == 0) {
        int gr = rowbase + row;
        int b = gr >> 1, e = gr & 1;
        const float4 xv = *(const float4*)(x + b * 4);
        float uv = u[b];
        float a0 = (xv.x - nm0) * is0;  // node0 feat0 (theta0)
        float a1 = (xv.z - nm1) * is1;  // node0 feat1 (v0)
        float b0 = (xv.y - nm0) * is0;  // node1 feat0
        float b1 = (xv.w - nm1) * is1;  // node1 feat1
        float s0 = e ? b0 : a0, s1 = e ? b1 : a1;   // sender  = node e
        float r0 = e ? a0 : b0, r1 = e ? a1 : b1;   // receiver= node 1-e
        float ea0 = (uv - em0) * ie0;
        val[0] = (short)f2bf(s0);  val[1] = (short)f2bf(s1);
        val[2] = (short)f2bf(r0);  val[3] = (short)f2bf(r1);
        val[4] = (short)f2bf(ea0); val[5] = (short)f2bf(cea1);
        val[6] = (short)f2bf(cea2); val[7] = (short)f2bf(1.0f);
      }
      *(bf16x8*)((char*)buf1 + off) = val;
    }
    __syncthreads();

    // ---------- G1': e1 = relu(A1 @ in32) ----------
    {
      f32x4 acc[4][2];
      #pragma unroll
      for (int m = 0; m < 4; ++m)
        #pragma unroll
        for (int n = 0; n < 2; ++n) acc[m][n] = (f32x4){0.f, 0.f, 0.f, 0.f};
      #pragma unroll
      for (int n = 0; n < 2; ++n) {
        int row = (Ng * 2 + n) * 16 + c15;
        bf16x8 B = *(const bf16x8*)((const char*)buf1 + row * 64 + ((g * 16) ^ ((row & 3) << 4)));
        #pragma unroll
        for (int m = 0; m < 4; ++m)
          acc[m][n] = __builtin_amdgcn_mfma_f32_16x16x32_bf16(A1[m], B, acc[m][n], 0, 0, 0);
      }
      #pragma unroll
      for (int m = 0; m < 4; ++m) {
        int jb2 = (jbw + m * 16 + g * 4) * 2;   // byte offset of j within a 256B row
        #pragma unroll
        for (int n = 0; n < 2; ++n) {
          int row = (Ng * 2 + n) * 16 + c15;
          f32x4 v = acc[m][n];
          uint2 pk;
          pk.x = (unsigned)f2bf(fmaxf(v[0], 0.f)) | ((unsigned)f2bf(fmaxf(v[1], 0.f)) << 16);
          pk.y = (unsigned)f2bf(fmaxf(v[2], 0.f)) | ((unsigned)f2bf(fmaxf(v[3], 0.f)) << 16);
          *(uint2*)((char*)e1buf + row * 256 + (jb2 ^ ((row & 7) << 4))) = pk;
        }
      }
    }
    __syncthreads();

    // ---------- G2': e2 = relu(A2 @ e1 + be2) ----------
    {
      f32x4 acc[4][2];
      #pragma unroll
      for (int m = 0; m < 4; ++m)
        #pragma unroll
        for (int n = 0; n < 2; ++n) acc[m][n] = (f32x4){0.f, 0.f, 0.f, 0.f};
      #pragma unroll
      for (int n = 0; n < 2; ++n) {
        int row = (Ng * 2 + n) * 16 + c15;
        int rb = row * 256, sw = (row & 7) << 4;
        #pragma unroll
        for (int kk = 0; kk < 4; ++kk) {
          bf16x8 B = *(const bf16x8*)((const char*)e1buf + rb + ((kk * 64 + g * 16) ^ sw));
          #pragma unroll
          for (int m = 0; m < 4; ++m)
            acc[m][n] = __builtin_amdgcn_mfma_f32_16x16x32_bf16(A2f[m][kk], B, acc[m][n], 0, 0, 0);
        }
      }
      #pragma unroll
      for (int m = 0; m < 4; ++m) {
        int jb = jbw + m * 16 + g * 4;
        f32x4 bz = *(const f32x4*)(be2 + jb);
        #pragma unroll
        for (int n = 0; n < 2; ++n) {
          int row = (Ng * 2 + n) * 16 + c15;
          f32x4 v = acc[m][n];
          uint2 pk;
          pk.x = (unsigned)f2bf(fmaxf(v[0] + bz[0], 0.f)) | ((unsigned)f2bf(fmaxf(v[1] + bz[1], 0.f)) << 16);
          pk.y = (unsigned)f2bf(fmaxf(v[2] + bz[2], 0.f)) | ((unsigned)f2bf(fmaxf(v[3] + bz[3], 0.f)) << 16);
          *(uint2*)((char*)buf1 + row * 256 + ((jb * 2) ^ ((row & 7) << 4))) = pk;
        }
      }
    }
    __syncthreads();

    // ---------- G3': hdd = relu(A3 @ e2[row^1] + node feats + bn1) ; G4 partials ----------
    {
      f32x4 acc[4][2];
      #pragma unroll
      for (int m = 0; m < 4; ++m)
        #pragma unroll
        for (int n = 0; n < 2; ++n) acc[m][n] = (f32x4){0.f, 0.f, 0.f, 0.f};
      #pragma unroll
      for (int n = 0; n < 2; ++n) {
        int row = ((Ng * 2 + n) * 16 + c15) ^ 1;     // aggregation = paired-row swap
        int rb = row * 256, sw = (row & 7) << 4;
        #pragma unroll
        for (int kk = 0; kk < 4; ++kk) {
          bf16x8 B = *(const bf16x8*)((const char*)buf1 + rb + ((kk * 64 + g * 16) ^ sw));
          #pragma unroll
          for (int m = 0; m < 4; ++m)
            acc[m][n] = __builtin_amdgcn_mfma_f32_16x16x32_bf16(A3f[m][kk], B, acc[m][n], 0, 0, 0);
        }
      }
      // node features for this lane's two output rows, recomputed from x (L1-hot)
      float xa[2], xb[2];
      #pragma unroll
      for (int n = 0; n < 2; ++n) {
        int row = (Ng * 2 + n) * 16 + c15;
        int gr = rowbase + row;
        int b = gr >> 1, k = gr & 1;
        xa[n] = (x[b * 4 + k]     - nm0) * is0;
        xb[n] = (x[b * 4 + k + 2] - nm1) * is1;
      }
      float p0[2] = {0.f, 0.f}, p1[2] = {0.f, 0.f};
      #pragma unroll
      for (int m = 0; m < 4; ++m) {
        int jb = jbw + m * 16 + g * 4;
        f32x4 bz  = *(const f32x4*)(bn1 + jb);
        f32x4 w0  = *(const f32x4*)(Wn1 + 10 * 128 + jb);
        f32x4 w1  = *(const f32x4*)(Wn1 + 11 * 128 + jb);
        f32x4 wlo = *(const f32x4*)(Wn2 + jb * 2);       // rows jb, jb+1 (c0,c1 each)
        f32x4 whi = *(const f32x4*)(Wn2 + jb * 2 + 4);   // rows jb+2, jb+3
        #pragma unroll
        for (int n = 0; n < 2; ++n) {
          f32x4 v = acc[m][n];
          #pragma unroll
          for (int r = 0; r < 4; ++r) {
            float h = fmaxf(v[r] + bz[r] + xa[n] * w0[r] + xb[n] * w1[r], 0.f);
            float wc0 = (r < 2) ? wlo[2 * r]     : whi[2 * r - 4];
            float wc1 = (r < 2) ? wlo[2 * r + 1] : whi[2 * r - 3];
            p0[n] += h * wc0;
            p1[n] += h * wc1;
          }
        }
      }
      // reduce across the 4 lane-groups (j sub-chunks)
      #pragma unroll
      for (int n = 0; n < 2; ++n) {
        p0[n] += __shfl_xor(p0[n], 16, 64); p0[n] += __shfl_xor(p0[n], 32, 64);
        p1[n] += __shfl_xor(p1[n], 16, 64); p1[n] += __shfl_xor(p1[n], 32, 64);
      }
      // write per-M-half partial deltas (alias: first 2KB of e1buf)
      if (g == 0) {
        float* pd = (float*)e1buf;
        #pragma unroll
        for (int n = 0; n < 2; ++n) {
          int row = (Ng * 2 + n) * 16 + c15;
          float2 w; w.x = p0[n]; w.y = p1[n];
          *(float2*)(pd + Mg * 256 + row * 2) = w;
        }
      }
    }
    __syncthreads();

    // ---------- stage4 final: combine M-halves, add bn2 and x, store ----------
    if (tid < 256) {
      const float* pd = (const float*)e1buf;
      int row = 2 * (tid >> 2) + (tid & 1);
      int c   = (tid >> 1) & 1;
      float d = pd[row * 2 + c] + pd[256 + row * 2 + c] + (c ? bn21 : bn20);
      int gi = rowbase * 2 + tid;      // == b*4 + (k + 2c), coalesced
      out[gi] = x[gi] + d;
    }
    // no trailing barrier needed: next stage0 writes buf1 (not read between bar4 and bar1')
  }
}

extern "C" void kernel_launch(void* const* d_in, const int* in_sizes, int n_in,
                              void* d_out, int out_size, void* d_ws, size_t ws_size,
                              hipStream_t stream) {
  const float* x   = (const float*)d_in[0];
  const float* u   = (const float*)d_in[1];
  const float* nm  = (const float*)d_in[2];
  const float* ns  = (const float*)d_in[3];
  const float* em  = (const float*)d_in[4];
  const float* es  = (const float*)d_in[5];
  const float* We1 = (const float*)d_in[6];
  const float* be1 = (const float*)d_in[7];
  const float* We2 = (const float*)d_in[8];
  const float* be2 = (const float*)d_in[9];
  const float* Wn1 = (const float*)d_in[10];
  const float* bn1 = (const float*)d_in[11];
  const float* Wn2 = (const float*)d_in[12];
  const float* bn2 = (const float*)d_in[13];
  unsigned short* wsA = (unsigned short*)d_ws;   // needs 73728 bytes
  float* out = (float*)d_out;

  gn_prep<<<144, 256, 0, stream>>>(We1, be1, We2, Wn1, wsA);
  gn_main<<<256, 512, 0, stream>>>(x, u, nm, ns, em, es, be2, bn1, Wn1, Wn2, bn2, wsA, out);
}

// Round 2
// 108.833 us; speedup vs baseline: 1.0017x; 1.0017x over previous
//
#include <hip/hip_runtime.h>

// Acrobot GN step, fused bf16-MFMA implementation.
// rows = 2*B (batch x {edge/node} index). Four layers:
//   G1': e1  = relu(A1 @ in32)         A1 = [We1[10:17] ; be1]^T  (K=32, bias folded via const-1 feature)
//   G2': e2  = relu(A2 @ e1 + be2)     A2 = We2^T                 (K=128)
//   G3': hdd = relu(A3 @ e2[row^1] + nodes@Wn1[10:12] + bn1)      A3 = Wn1[12:140]^T (K=128)
//   G4 : delta = hdd^T @ Wn2 + bn2  (VALU from MFMA accumulators + shfl butterfly)
// out = x + scatter(delta)
//
// R1 change: __launch_bounds__(512, 1). R0 had (512,2) -> compiler capped at 128 VGPR
// and spilled ~80 regs of weight fragments -> 145 MB of scratch HBM traffic per dispatch.

typedef __attribute__((ext_vector_type(8))) short bf16x8;
typedef __attribute__((ext_vector_type(4))) float f32x4;

__device__ __forceinline__ unsigned short f2bf(float f) {
  union { float f; unsigned u; } v; v.f = f;
  return (unsigned short)((v.u + 0x7FFFu + ((v.u >> 16) & 1u)) >> 16);  // RNE
}

// ---------------- weight prep: build bf16 transposed A-operand images in ws ----------------
// ws layout (shorts): A1 [128j][32k] @0 ; A2=We2^T [128j][128k] @4096 ; A3=Wn1[12:]^T @20480
__global__ void gn_prep(const float* __restrict__ We1, const float* __restrict__ be1,
                        const float* __restrict__ We2, const float* __restrict__ Wn1,
                        unsigned short* __restrict__ wsA) {
  int t = blockIdx.x * 256 + threadIdx.x;
  if (t < 4096) {
    int j = t >> 5, k = t & 31;
    float v = (k < 7) ? We1[(10 + k) * 128 + j] : ((k == 7) ? be1[j] : 0.0f);
    wsA[t] = f2bf(v);
  } else if (t < 20480) {
    int t2 = t - 4096; int j = t2 >> 7, k = t2 & 127;
    wsA[t] = f2bf(We2[k * 128 + j]);
  } else if (t < 36864) {
    int t2 = t - 20480; int j = t2 >> 7, k = t2 & 127;
    wsA[t] = f2bf(Wn1[(12 + k) * 128 + j]);
  }
}

// ---------------- main fused kernel ----------------
#define NTILES 2048   // 262144 rows / 128 rows per tile

__global__ __launch_bounds__(512, 1) void gn_main(
    const float* __restrict__ x, const float* __restrict__ u,
    const float* __restrict__ nmean, const float* __restrict__ nstd,
    const float* __restrict__ emean, const float* __restrict__ estd,
    const float* __restrict__ be2, const float* __restrict__ bn1,
    const float* __restrict__ Wn1, const float* __restrict__ Wn2,
    const float* __restrict__ bn2,
    const unsigned short* __restrict__ wsA,
    float* __restrict__ out)
{
  // 64KB LDS total. buf1 prefix (8KB) doubles as in32 staging; e1buf prefix (2KB) doubles as pdelta.
  __shared__ __align__(16) unsigned short e1buf[128 * 128];  // e1 [row][128k] bf16, swizzled
  __shared__ __align__(16) unsigned short buf1[128 * 128];   // in32 [row][32k] then e2 [row][128k]

  const int tid  = threadIdx.x;
  const int lane = tid & 63;
  const int wave = tid >> 6;
  const int Mg   = wave & 1;    // M half (feature dim half)
  const int Ng   = wave >> 1;   // N group (row groups of 32)
  const int c15  = lane & 15;
  const int g    = lane >> 4;   // 0..3

  // ---- A-operand fragments, loaded once, held in VGPRs (16+64+64 = 144 regs) ----
  bf16x8 A1[4], A2f[4][4], A3f[4][4];
  const int jbw = Mg * 64;
  #pragma unroll
  for (int m = 0; m < 4; ++m) {
    int j = jbw + m * 16 + c15;
    A1[m] = *(const bf16x8*)(wsA + j * 32 + g * 8);
    #pragma unroll
    for (int kk = 0; kk < 4; ++kk) {
      A2f[m][kk] = *(const bf16x8*)(wsA + 4096  + j * 128 + kk * 32 + g * 8);
      A3f[m][kk] = *(const bf16x8*)(wsA + 20480 + j * 128 + kk * 32 + g * 8);
    }
  }

  const float nm0 = nmean[0], nm1 = nmean[1];
  const float is0 = 1.0f / nstd[0], is1 = 1.0f / nstd[1];
  const float em0 = emean[0], ie0 = 1.0f / estd[0];
  const float cea1 = (0.0f - emean[1]) / estd[1];
  const float cea2 = (0.0f - emean[2]) / estd[2];
  const float bn20 = bn2[0], bn21 = bn2[1];

  for (int tile = blockIdx.x; tile < NTILES; tile += gridDim.x) {
    const int rowbase = tile * 128;

    // ---------- stage0: build in32 (bf16, 32 feats/row; feats 8..31 zero) into buf1 prefix ----------
    {
      int row = tid & 127;
      int cc  = tid >> 7;                       // 16B chunk 0..3 (wave-uniform)
      int off = row * 64 + ((cc * 16) ^ ((row & 3) << 4));
      bf16x8 val;
      #pragma unroll
      for (int i = 0; i < 8; ++i) val[i] = 0;
      if (cc == 0) {
        int gr = rowbase + row;
        int b = gr >> 1, e = gr & 1;
        const float4 xv = *(const float4*)(x + b * 4);
        float uv = u[b];
        float a0 = (xv.x - nm0) * is0;  // node0 feat0 (theta0)
        float a1 = (xv.z - nm1) * is1;  // node0 feat1 (v0)
        float b0 = (xv.y - nm0) * is0;  // node1 feat0
        float b1 = (xv.w - nm1) * is1;  // node1 feat1
        float s0 = e ? b0 : a0, s1 = e ? b1 : a1;   // sender  = node e
        float r0 = e ? a0 : b0, r1 = e ? a1 : b1;   // receiver= node 1-e
        float ea0 = (uv - em0) * ie0;
        val[0] = (short)f2bf(s0);  val[1] = (short)f2bf(s1);
        val[2] = (short)f2bf(r0);  val[3] = (short)f2bf(r1);
        val[4] = (short)f2bf(ea0); val[5] = (short)f2bf(cea1);
        val[6] = (short)f2bf(cea2); val[7] = (short)f2bf(1.0f);
      }
      *(bf16x8*)((char*)buf1 + off) = val;
    }
    __syncthreads();

    // ---------- G1': e1 = relu(A1 @ in32) ----------
    {
      f32x4 acc[4][2];
      #pragma unroll
      for (int m = 0; m < 4; ++m)
        #pragma unroll
        for (int n = 0; n < 2; ++n) acc[m][n] = (f32x4){0.f, 0.f, 0.f, 0.f};
      #pragma unroll
      for (int n = 0; n < 2; ++n) {
        int row = (Ng * 2 + n) * 16 + c15;
        bf16x8 B = *(const bf16x8*)((const char*)buf1 + row * 64 + ((g * 16) ^ ((row & 3) << 4)));
        #pragma unroll
        for (int m = 0; m < 4; ++m)
          acc[m][n] = __builtin_amdgcn_mfma_f32_16x16x32_bf16(A1[m], B, acc[m][n], 0, 0, 0);
      }
      #pragma unroll
      for (int m = 0; m < 4; ++m) {
        int jb2 = (jbw + m * 16 + g * 4) * 2;   // byte offset of j within a 256B row
        #pragma unroll
        for (int n = 0; n < 2; ++n) {
          int row = (Ng * 2 + n) * 16 + c15;
          f32x4 v = acc[m][n];
          uint2 pk;
          pk.x = (unsigned)f2bf(fmaxf(v[0], 0.f)) | ((unsigned)f2bf(fmaxf(v[1], 0.f)) << 16);
          pk.y = (unsigned)f2bf(fmaxf(v[2], 0.f)) | ((unsigned)f2bf(fmaxf(v[3], 0.f)) << 16);
          *(uint2*)((char*)e1buf + row * 256 + (jb2 ^ ((row & 7) << 4))) = pk;
        }
      }
    }
    __syncthreads();

    // ---------- G2': e2 = relu(A2 @ e1 + be2) ----------
    {
      f32x4 acc[4][2];
      #pragma unroll
      for (int m = 0; m < 4; ++m)
        #pragma unroll
        for (int n = 0; n < 2; ++n) acc[m][n] = (f32x4){0.f, 0.f, 0.f, 0.f};
      #pragma unroll
      for (int n = 0; n < 2; ++n) {
        int row = (Ng * 2 + n) * 16 + c15;
        int rb = row * 256, sw = (row & 7) << 4;
        #pragma unroll
        for (int kk = 0; kk < 4; ++kk) {
          bf16x8 B = *(const bf16x8*)((const char*)e1buf + rb + ((kk * 64 + g * 16) ^ sw));
          #pragma unroll
          for (int m = 0; m < 4; ++m)
            acc[m][n] = __builtin_amdgcn_mfma_f32_16x16x32_bf16(A2f[m][kk], B, acc[m][n], 0, 0, 0);
        }
      }
      #pragma unroll
      for (int m = 0; m < 4; ++m) {
        int jb = jbw + m * 16 + g * 4;
        f32x4 bz = *(const f32x4*)(be2 + jb);
        #pragma unroll
        for (int n = 0; n < 2; ++n) {
          int row = (Ng * 2 + n) * 16 + c15;
          f32x4 v = acc[m][n];
          uint2 pk;
          pk.x = (unsigned)f2bf(fmaxf(v[0] + bz[0], 0.f)) | ((unsigned)f2bf(fmaxf(v[1] + bz[1], 0.f)) << 16);
          pk.y = (unsigned)f2bf(fmaxf(v[2] + bz[2], 0.f)) | ((unsigned)f2bf(fmaxf(v[3] + bz[3], 0.f)) << 16);
          *(uint2*)((char*)buf1 + row * 256 + ((jb * 2) ^ ((row & 7) << 4))) = pk;
        }
      }
    }
    __syncthreads();

    // ---------- G3': hdd = relu(A3 @ e2[row^1] + node feats + bn1) ; G4 partials ----------
    {
      f32x4 acc[4][2];
      #pragma unroll
      for (int m = 0; m < 4; ++m)
        #pragma unroll
        for (int n = 0; n < 2; ++n) acc[m][n] = (f32x4){0.f, 0.f, 0.f, 0.f};
      #pragma unroll
      for (int n = 0; n < 2; ++n) {
        int row = ((Ng * 2 + n) * 16 + c15) ^ 1;     // aggregation = paired-row swap
        int rb = row * 256, sw = (row & 7) << 4;
        #pragma unroll
        for (int kk = 0; kk < 4; ++kk) {
          bf16x8 B = *(const bf16x8*)((const char*)buf1 + rb + ((kk * 64 + g * 16) ^ sw));
          #pragma unroll
          for (int m = 0; m < 4; ++m)
            acc[m][n] = __builtin_amdgcn_mfma_f32_16x16x32_bf16(A3f[m][kk], B, acc[m][n], 0, 0, 0);
        }
      }
      // node features for this lane's two output rows, recomputed from x (L1-hot)
      float xa[2], xb[2];
      #pragma unroll
      for (int n = 0; n < 2; ++n) {
        int row = (Ng * 2 + n) * 16 + c15;
        int gr = rowbase + row;
        int b = gr >> 1, k = gr & 1;
        xa[n] = (x[b * 4 + k]     - nm0) * is0;
        xb[n] = (x[b * 4 + k + 2] - nm1) * is1;
      }
      float p0[2] = {0.f, 0.f}, p1[2] = {0.f, 0.f};
      #pragma unroll
      for (int m = 0; m < 4; ++m) {
        int jb = jbw + m * 16 + g * 4;
        f32x4 bz  = *(const f32x4*)(bn1 + jb);
        f32x4 w0  = *(const f32x4*)(Wn1 + 10 * 128 + jb);
        f32x4 w1  = *(const f32x4*)(Wn1 + 11 * 128 + jb);
        f32x4 wlo = *(const f32x4*)(Wn2 + jb * 2);       // rows jb, jb+1 (c0,c1 each)
        f32x4 whi = *(const f32x4*)(Wn2 + jb * 2 + 4);   // rows jb+2, jb+3
        #pragma unroll
        for (int n = 0; n < 2; ++n) {
          f32x4 v = acc[m][n];
          #pragma unroll
          for (int r = 0; r < 4; ++r) {
            float h = fmaxf(v[r] + bz[r] + xa[n] * w0[r] + xb[n] * w1[r], 0.f);
            float wc0 = (r < 2) ? wlo[2 * r]     : whi[2 * r - 4];
            float wc1 = (r < 2) ? wlo[2 * r + 1] : whi[2 * r - 3];
            p0[n] += h * wc0;
            p1[n] += h * wc1;
          }
        }
      }
      // reduce across the 4 lane-groups (j sub-chunks)
      #pragma unroll
      for (int n = 0; n < 2; ++n) {
        p0[n] += __shfl_xor(p0[n], 16, 64); p0[n] += __shfl_xor(p0[n], 32, 64);
        p1[n] += __shfl_xor(p1[n], 16, 64); p1[n] += __shfl_xor(p1[n], 32, 64);
      }
      // write per-M-half partial deltas (alias: first 2KB of e1buf)
      if (g == 0) {
        float* pd = (float*)e1buf;
        #pragma unroll
        for (int n = 0; n < 2; ++n) {
          int row = (Ng * 2 + n) * 16 + c15;
          float2 w; w.x = p0[n]; w.y = p1[n];
          *(float2*)(pd + Mg * 256 + row * 2) = w;
        }
      }
    }
    __syncthreads();

    // ---------- stage4 final: combine M-halves, add bn2 and x, store ----------
    if (tid < 256) {
      const float* pd = (const float*)e1buf;
      int row = 2 * (tid >> 2) + (tid & 1);
      int c   = (tid >> 1) & 1;
      float d = pd[row * 2 + c] + pd[256 + row * 2 + c] + (c ? bn21 : bn20);
      int gi = rowbase * 2 + tid;      // == b*4 + (k + 2c), coalesced
      out[gi] = x[gi] + d;
    }
    // no trailing barrier needed: next stage0 writes buf1 (not read between bar4 and bar1')
  }
}

extern "C" void kernel_launch(void* const* d_in, const int* in_sizes, int n_in,
                              void* d_out, int out_size, void* d_ws, size_t ws_size,
                              hipStream_t stream) {
  const float* x   = (const float*)d_in[0];
  const float* u   = (const float*)d_in[1];
  const float* nm  = (const float*)d_in[2];
  const float* ns  = (const float*)d_in[3];
  const float* em  = (const float*)d_in[4];
  const float* es  = (const float*)d_in[5];
  const float* We1 = (const float*)d_in[6];
  const float* be1 = (const float*)d_in[7];
  const float* We2 = (const float*)d_in[8];
  const float* be2 = (const float*)d_in[9];
  const float* Wn1 = (const float*)d_in[10];
  const float* bn1 = (const float*)d_in[11];
  const float* Wn2 = (const float*)d_in[12];
  const float* bn2 = (const float*)d_in[13];
  unsigned short* wsA = (unsigned short*)d_ws;   // needs 73728 bytes
  float* out = (float*)d_out;

  gn_prep<<<144, 256, 0, stream>>>(We1, be1, We2, Wn1, wsA);
  gn_main<<<256, 512, 0, stream>>>(x, u, nm, ns, em, es, be2, bn1, Wn1, Wn2, bn2, wsA, out);
}

// Round 3
// 59.584 us; speedup vs baseline: 1.8296x; 1.8265x over previous
//
#include <hip/hip_runtime.h>

// Acrobot GN step, fused bf16-MFMA implementation. rows = 2*B.
//   G1: e1  = relu(A1 @ in32)            A1 = [We1[10:17];be1]^T, K=32 (bias via const-1 feat)
//   G2: e2  = relu(A2 @ e1 + be2)        A2 = We2^T, K=128
//   G3: hdd = relu(A3 @ [e2[row^1]; nodefeat]) K=160: main 128 = Wn1[12:140]^T over swapped rows,
//             ext 32 = [Wn1r10, Wn1r11, bn1, 0...] x B4(xa, xb, 1) built in-register
//   G4: delta = A4 @ hdd                 A4 = Wn2^T padded [16][128], K=128 MFMA
// out = x + scatter(delta) + bn2
//
// R2: amdgpu_waves_per_eu(2,2) caps allocator occupancy target -> 256-VGPR budget
//     (R0/R1: LDS-derived 4 waves/SIMD target -> 128-reg cap -> ~70 spilled regs -> 100MB scratch).
//     G3 K-fold + MFMA G4 remove the 80 hoisted epilogue constants.

typedef __attribute__((ext_vector_type(8))) short bf16x8;
typedef __attribute__((ext_vector_type(4))) float f32x4;

__device__ __forceinline__ unsigned short f2bf(float f) {
  union { float f; unsigned u; } v; v.f = f;
  return (unsigned short)((v.u + 0x7FFFu + ((v.u >> 16) & 1u)) >> 16);  // RNE
}

// ---------------- weight prep: bf16 transposed A-operand images in ws ----------------
// shorts: A1 [128][32] @0 ; A2 [128][128] @4096 ; A3 [128][128] @20480 ;
//         A3ext [128][32] @36864 ; A4 [16][128] @40960 ; total 43008 shorts = 86016 B
__global__ void gn_prep(const float* __restrict__ We1, const float* __restrict__ be1,
                        const float* __restrict__ We2, const float* __restrict__ Wn1,
                        const float* __restrict__ bn1, const float* __restrict__ Wn2,
                        unsigned short* __restrict__ wsA) {
  int t = blockIdx.x * 256 + threadIdx.x;
  if (t < 4096) {                       // A1: k<7 -> We1 rows 10..16 ; k==7 -> be1
    int j = t >> 5, k = t & 31;
    float v = (k < 7) ? We1[(10 + k) * 128 + j] : ((k == 7) ? be1[j] : 0.0f);
    wsA[t] = f2bf(v);
  } else if (t < 20480) {               // A2 = We2^T
    int t2 = t - 4096; int j = t2 >> 7, k = t2 & 127;
    wsA[t] = f2bf(We2[k * 128 + j]);
  } else if (t < 36864) {               // A3 main = Wn1[12:140]^T
    int t2 = t - 20480; int j = t2 >> 7, k = t2 & 127;
    wsA[t] = f2bf(Wn1[(12 + k) * 128 + j]);
  } else if (t < 40960) {               // A3 ext: c0=Wn1r10, c1=Wn1r11, c2=bn1
    int t2 = t - 36864; int j = t2 >> 5, c = t2 & 31;
    float v = (c == 0) ? Wn1[10 * 128 + j] : (c == 1) ? Wn1[11 * 128 + j]
            : (c == 2) ? bn1[j] : 0.0f;
    wsA[t] = f2bf(v);
  } else if (t < 43008) {               // A4 = Wn2^T padded to 16 rows
    int t2 = t - 40960; int jp = t2 >> 7, k = t2 & 127;
    wsA[t] = f2bf((jp < 2) ? Wn2[k * 2 + jp] : 0.0f);
  }
}

// ---------------- main fused kernel ----------------
#define NTILES 2048   // 262144 rows / 128 rows per tile

__global__ __launch_bounds__(512) __attribute__((amdgpu_waves_per_eu(2, 2)))
void gn_main(
    const float* __restrict__ x, const float* __restrict__ u,
    const float* __restrict__ nmean, const float* __restrict__ nstd,
    const float* __restrict__ emean, const float* __restrict__ estd,
    const float* __restrict__ be2, const float* __restrict__ bn2,
    const unsigned short* __restrict__ wsA,
    float* __restrict__ out)
{
  // bufA: in32 (stage0->G1, 8KB) then e2 (G2->G3) then pdelta @30720 (G4->stage4)
  // bufB: e1 (G1->G2) then hdd (G3->G4)
  __shared__ __align__(16) unsigned short bufA[128 * 128];
  __shared__ __align__(16) unsigned short bufB[128 * 128];

  const int tid  = threadIdx.x;
  const int lane = tid & 63;
  const int wave = tid >> 6;
  const int Mg   = wave & 1;    // M half (feature dim half)
  const int Ng   = wave >> 1;   // N group (row groups of 32)
  const int c15  = lane & 15;
  const int g    = lane >> 4;   // 0..3

  // ---- A-operand fragments, loaded once, held in VGPRs ----
  bf16x8 A1f[4], A2f[4][4], A3f[4][5], A4f[4];
  const int jbw = Mg * 64;
  #pragma unroll
  for (int m = 0; m < 4; ++m) {
    int j = jbw + m * 16 + c15;
    A1f[m] = *(const bf16x8*)(wsA + j * 32 + g * 8);
    #pragma unroll
    for (int kk = 0; kk < 4; ++kk) {
      A2f[m][kk] = *(const bf16x8*)(wsA + 4096  + j * 128 + kk * 32 + g * 8);
      A3f[m][kk] = *(const bf16x8*)(wsA + 20480 + j * 128 + kk * 32 + g * 8);
    }
    A3f[m][4] = *(const bf16x8*)(wsA + 36864 + j * 32 + g * 8);
  }
  #pragma unroll
  for (int kk = 0; kk < 4; ++kk)
    A4f[kk] = *(const bf16x8*)(wsA + 40960 + c15 * 128 + kk * 32 + g * 8);

  const float nm0 = nmean[0], nm1 = nmean[1];
  const float is0 = 1.0f / nstd[0], is1 = 1.0f / nstd[1];
  const float em0 = emean[0], ie0 = 1.0f / estd[0];
  const float cea1 = (0.0f - emean[1]) / estd[1];
  const float cea2 = (0.0f - emean[2]) / estd[2];
  const float bn20 = bn2[0], bn21 = bn2[1];

  for (int tile = blockIdx.x; tile < NTILES; tile += gridDim.x) {
    const int rowbase = tile * 128;

    // ---------- stage0: build in32 (bf16, k=0..7 used) into bufA prefix ----------
    {
      int row = tid & 127;
      int cc  = tid >> 7;                       // 16B chunk 0..3 (wave-uniform)
      int off = row * 64 + ((cc * 16) ^ ((row & 3) << 4));
      bf16x8 val;
      #pragma unroll
      for (int i = 0; i < 8; ++i) val[i] = 0;
      if (cc == 0) {
        int gr = rowbase + row;
        int b = gr >> 1, e = gr & 1;
        const float4 xv = *(const float4*)(x + b * 4);
        float uv = u[b];
        float a0 = (xv.x - nm0) * is0;  // node0 theta
        float a1 = (xv.z - nm1) * is1;  // node0 v
        float b0 = (xv.y - nm0) * is0;  // node1 theta
        float b1 = (xv.w - nm1) * is1;  // node1 v
        float s0 = e ? b0 : a0, s1 = e ? b1 : a1;   // sender  = node e
        float r0 = e ? a0 : b0, r1 = e ? a1 : b1;   // receiver= node 1-e
        float ea0 = (uv - em0) * ie0;
        val[0] = (short)f2bf(s0);  val[1] = (short)f2bf(s1);
        val[2] = (short)f2bf(r0);  val[3] = (short)f2bf(r1);
        val[4] = (short)f2bf(ea0); val[5] = (short)f2bf(cea1);
        val[6] = (short)f2bf(cea2); val[7] = (short)f2bf(1.0f);
      }
      *(bf16x8*)((char*)bufA + off) = val;
    }
    __syncthreads();

    // ---------- G1: e1 = relu(A1 @ in32) -> bufB ----------
    {
      f32x4 acc[4][2];
      #pragma unroll
      for (int m = 0; m < 4; ++m)
        #pragma unroll
        for (int n = 0; n < 2; ++n) acc[m][n] = (f32x4){0.f, 0.f, 0.f, 0.f};
      #pragma unroll
      for (int n = 0; n < 2; ++n) {
        int row = (Ng * 2 + n) * 16 + c15;
        bf16x8 B = *(const bf16x8*)((const char*)bufA + row * 64 + ((g * 16) ^ ((row & 3) << 4)));
        #pragma unroll
        for (int m = 0; m < 4; ++m)
          acc[m][n] = __builtin_amdgcn_mfma_f32_16x16x32_bf16(A1f[m], B, acc[m][n], 0, 0, 0);
      }
      #pragma unroll
      for (int m = 0; m < 4; ++m) {
        int jb2 = (jbw + m * 16 + g * 4) * 2;
        #pragma unroll
        for (int n = 0; n < 2; ++n) {
          int row = (Ng * 2 + n) * 16 + c15;
          f32x4 v = acc[m][n];
          uint2 pk;
          pk.x = (unsigned)f2bf(fmaxf(v[0], 0.f)) | ((unsigned)f2bf(fmaxf(v[1], 0.f)) << 16);
          pk.y = (unsigned)f2bf(fmaxf(v[2], 0.f)) | ((unsigned)f2bf(fmaxf(v[3], 0.f)) << 16);
          *(uint2*)((char*)bufB + row * 256 + (jb2 ^ ((row & 7) << 4))) = pk;
        }
      }
    }
    __syncthreads();

    // ---------- G2: e2 = relu(A2 @ e1 + be2) -> bufA ----------
    {
      f32x4 acc[4][2];
      #pragma unroll
      for (int m = 0; m < 4; ++m)
        #pragma unroll
        for (int n = 0; n < 2; ++n) acc[m][n] = (f32x4){0.f, 0.f, 0.f, 0.f};
      #pragma unroll
      for (int n = 0; n < 2; ++n) {
        int row = (Ng * 2 + n) * 16 + c15;
        int rb = row * 256, sw = (row & 7) << 4;
        #pragma unroll
        for (int kk = 0; kk < 4; ++kk) {
          bf16x8 B = *(const bf16x8*)((const char*)bufB + rb + ((kk * 64 + g * 16) ^ sw));
          #pragma unroll
          for (int m = 0; m < 4; ++m)
            acc[m][n] = __builtin_amdgcn_mfma_f32_16x16x32_bf16(A2f[m][kk], B, acc[m][n], 0, 0, 0);
        }
      }
      #pragma unroll
      for (int m = 0; m < 4; ++m) {
        int jb = jbw + m * 16 + g * 4;
        f32x4 bz = *(const f32x4*)(be2 + jb);
        #pragma unroll
        for (int n = 0; n < 2; ++n) {
          int row = (Ng * 2 + n) * 16 + c15;
          f32x4 v = acc[m][n];
          uint2 pk;
          pk.x = (unsigned)f2bf(fmaxf(v[0] + bz[0], 0.f)) | ((unsigned)f2bf(fmaxf(v[1] + bz[1], 0.f)) << 16);
          pk.y = (unsigned)f2bf(fmaxf(v[2] + bz[2], 0.f)) | ((unsigned)f2bf(fmaxf(v[3] + bz[3], 0.f)) << 16);
          *(uint2*)((char*)bufA + row * 256 + ((jb * 2) ^ ((row & 7) << 4))) = pk;
        }
      }
    }
    __syncthreads();

    // ---------- G3: hdd = relu(A3 @ [e2[row^1]; nodefeat]) -> bufB ----------
    {
      f32x4 acc[4][2];
      #pragma unroll
      for (int m = 0; m < 4; ++m)
        #pragma unroll
        for (int n = 0; n < 2; ++n) acc[m][n] = (f32x4){0.f, 0.f, 0.f, 0.f};
      #pragma unroll
      for (int n = 0; n < 2; ++n) {
        int rr0 = (Ng * 2 + n) * 16 + c15;
        int rsw = rr0 ^ 1;                       // aggregation = paired-row swap
        int rb = rsw * 256, sw = (rsw & 7) << 4;
        #pragma unroll
        for (int kk = 0; kk < 4; ++kk) {
          bf16x8 B = *(const bf16x8*)((const char*)bufA + rb + ((kk * 64 + g * 16) ^ sw));
          #pragma unroll
          for (int m = 0; m < 4; ++m)
            acc[m][n] = __builtin_amdgcn_mfma_f32_16x16x32_bf16(A3f[m][kk], B, acc[m][n], 0, 0, 0);
        }
        // K-chunk 4: node features (xa, xb, 1) live only in g==0 lanes' k=128..130
        bf16x8 B4;
        #pragma unroll
        for (int i = 0; i < 8; ++i) B4[i] = 0;
        if (g == 0) {
          int gr = rowbase + rr0;
          int b = gr >> 1, k = gr & 1;
          float xa = (x[b * 4 + k]     - nm0) * is0;
          float xb = (x[b * 4 + k + 2] - nm1) * is1;
          B4[0] = (short)f2bf(xa); B4[1] = (short)f2bf(xb);
          B4[2] = (short)0x3F80;   // bf16 1.0
        }
        #pragma unroll
        for (int m = 0; m < 4; ++m)
          acc[m][n] = __builtin_amdgcn_mfma_f32_16x16x32_bf16(A3f[m][4], B4, acc[m][n], 0, 0, 0);
      }
      #pragma unroll
      for (int m = 0; m < 4; ++m) {
        int jb2 = (jbw + m * 16 + g * 4) * 2;
        #pragma unroll
        for (int n = 0; n < 2; ++n) {
          int row = (Ng * 2 + n) * 16 + c15;
          f32x4 v = acc[m][n];
          uint2 pk;
          pk.x = (unsigned)f2bf(fmaxf(v[0], 0.f)) | ((unsigned)f2bf(fmaxf(v[1], 0.f)) << 16);
          pk.y = (unsigned)f2bf(fmaxf(v[2], 0.f)) | ((unsigned)f2bf(fmaxf(v[3], 0.f)) << 16);
          *(uint2*)((char*)bufB + row * 256 + (jb2 ^ ((row & 7) << 4))) = pk;
        }
      }
    }
    __syncthreads();

    // ---------- G4: delta = A4 @ hdd (each wave does one 16-row group) ----------
    {
      int rr = (Ng * 2 + Mg) * 16 + c15;
      int rb = rr * 256, sw = (rr & 7) << 4;
      f32x4 a4 = (f32x4){0.f, 0.f, 0.f, 0.f};
      #pragma unroll
      for (int kk = 0; kk < 4; ++kk) {
        bf16x8 B = *(const bf16x8*)((const char*)bufB + rb + ((kk * 64 + g * 16) ^ sw));
        a4 = __builtin_amdgcn_mfma_f32_16x16x32_bf16(A4f[kk], B, a4, 0, 0, 0);
      }
      if (g == 0) {          // rows j'=0,1 of D = delta c0,c1 for col rr
        float2 w; w.x = a4[0]; w.y = a4[1];
        *(float2*)((char*)bufA + 30720 + rr * 8) = w;
      }
    }
    __syncthreads();

    // ---------- stage4: add bn2 and x, coalesced store ----------
    if (tid < 256) {
      const float* pd = (const float*)((const char*)bufA + 30720);
      int rr = 2 * (tid >> 2) + (tid & 1);
      int c  = (tid >> 1) & 1;
      float d = pd[rr * 2 + c] + (c ? bn21 : bn20);
      int gi = rowbase * 2 + tid;      // == b*4 + (k + 2c), coalesced
      out[gi] = x[gi] + d;
    }
    // next stage0 writes bufA[0..8KB) — disjoint from pdelta @30720, no barrier needed
  }
}

extern "C" void kernel_launch(void* const* d_in, const int* in_sizes, int n_in,
                              void* d_out, int out_size, void* d_ws, size_t ws_size,
                              hipStream_t stream) {
  const float* x   = (const float*)d_in[0];
  const float* u   = (const float*)d_in[1];
  const float* nm  = (const float*)d_in[2];
  const float* ns  = (const float*)d_in[3];
  const float* em  = (const float*)d_in[4];
  const float* es  = (const float*)d_in[5];
  const float* We1 = (const float*)d_in[6];
  const float* be1 = (const float*)d_in[7];
  const float* We2 = (const float*)d_in[8];
  const float* be2 = (const float*)d_in[9];
  const float* Wn1 = (const float*)d_in[10];
  const float* bn1 = (const float*)d_in[11];
  const float* Wn2 = (const float*)d_in[12];
  const float* bn2 = (const float*)d_in[13];
  unsigned short* wsA = (unsigned short*)d_ws;   // needs 86016 bytes
  float* out = (float*)d_out;

  gn_prep<<<168, 256, 0, stream>>>(We1, be1, We2, Wn1, bn1, Wn2, wsA);
  gn_main<<<256, 512, 0, stream>>>(x, u, nm, ns, em, es, be2, bn2, wsA, out);
}